// Round 8
// baseline (792.208 us; speedup 1.0000x reference)
//
#include <hip/hip_runtime.h>

typedef unsigned long long ull;

#define HIDDEN 32
#define SORTK 30
#define KCAP 256              // max nodes/graph fast path (mean 122, sd 11; >12 sigma)
#define W1STR 164             // w1s per-o stride (dwords), == 4 mod 32 -> 2-way free
#define W2STR 100             // w2s per-o stride (dwords), == 4 mod 32 -> 2-way free
#define SINROWS 36            // sin_ rows (30 used, pad for OOB lanes, zeroed)
#define C1ROWS 28             // c1 rows (26 used, pad, zeroed)
#define C2ROW 33              // c2 row stride
#define BSH 7                 // 128 nodes per bucket
#define BNODES (1 << BSH)
#define BCAP 1536
#define HMAX 2048
#define NSEG 256
#define SRC_BITS 18
#define SRC_MASK ((1u << SRC_BITS) - 1)
#define EID_SH  SRC_BITS
#define LD_SH   (SRC_BITS + 22)

static inline int ceil_div_i(long long a, int b){ return (int)((a + b - 1) / b); }

// ---------------- phase 1: per-segment LDS histogram ----------------
__global__ __launch_bounds__(1024) void hist_kernel(const int* __restrict__ dsts,
                                                    int* __restrict__ hist,
                                                    int E, int NB, int segsz){
  __shared__ int h[HMAX];
  for (int i = threadIdx.x; i < NB; i += 1024) h[i] = 0;
  __syncthreads();
  int seg = blockIdx.x;
  int e0 = seg * segsz;
  int e1 = e0 + segsz; if (e1 > E) e1 = E;
  for (int e = e0 + threadIdx.x; e < e1; e += 1024)
    atomicAdd(&h[dsts[e] >> BSH], 1);
  __syncthreads();
  for (int i = threadIdx.x; i < NB; i += 1024) hist[seg * NB + i] = h[i];
}

// ---------------- phase 2a: per-bucket running prefix over segments ----------------
__global__ __launch_bounds__(256) void segscanA(const int* __restrict__ hist,
                                                int* __restrict__ segoff,
                                                int* __restrict__ btot,
                                                int NB, int S){
  int b = blockIdx.x * 256 + threadIdx.x;
  if (b >= NB) return;
  int run = 0;
  for (int s = 0; s < S; s++){
    int v = hist[s * NB + b];
    segoff[s * NB + b] = run;
    run += v;
  }
  btot[b] = run;
}

// ---------------- phase 2b: exclusive scan of bucket totals (1 block) ----------------
__global__ __launch_bounds__(1024) void segscanB(const int* __restrict__ btot,
                                                 int* __restrict__ bbase, int NB){
  int t = threadIdx.x;
  int b0 = t * 2, b1 = t * 2 + 1;
  int v0 = (b0 < NB) ? btot[b0] : 0;
  int v1 = (b1 < NB) ? btot[b1] : 0;
  int pair = v0 + v1;
  int lane = t & 63, wid = t >> 6;
  int x = pair;
  for (int o = 1; o < 64; o <<= 1){ int y = __shfl_up(x, o, 64); if (lane >= o) x += y; }
  __shared__ int wsum[16]; __shared__ int woff[16];
  if (lane == 63) wsum[wid] = x;
  __syncthreads();
  if (t == 0){ int run = 0; for (int w = 0; w < 16; w++){ woff[w] = run; run += wsum[w]; } }
  __syncthreads();
  int excl = x - pair + woff[wid];
  if (b0 < NB) bbase[b0] = excl;
  if (b1 < NB) bbase[b1] = excl + v0;
}

// ---------------- phase 3: scatter 64-bit (ld,eid,src), block-private regions ------
__global__ __launch_bounds__(1024) void scatter_kernel(const int* __restrict__ dsts,
                                                       const int* __restrict__ srcs,
                                                       const int* __restrict__ segoff,
                                                       const int* __restrict__ bbase,
                                                       ull* __restrict__ staging,
                                                       int E, int NB, int segsz){
  __shared__ int cur[HMAX];
  int seg = blockIdx.x;
  for (int i = threadIdx.x; i < NB; i += 1024) cur[i] = segoff[seg * NB + i] + bbase[i];
  __syncthreads();
  int e0 = seg * segsz;
  int e1 = e0 + segsz; if (e1 > E) e1 = E;
  for (int e = e0 + threadIdx.x; e < e1; e += 1024){
    int d = dsts[e];
    int slot = atomicAdd(&cur[d >> BSH], 1);
    staging[slot] = ((ull)(d & (BNODES - 1)) << LD_SH) | ((ull)e << EID_SH)
                  | (ull)(unsigned)srcs[e];
  }
}

// ---------------- phase 4: per-bucket LDS sort + dis + offs + CSR ----------------
__global__ __launch_bounds__(BNODES) void bucket_sort_kernel(
    const int* __restrict__ bbase, const ull* __restrict__ staging,
    int* __restrict__ csr, int* __restrict__ offs,
    float* __restrict__ dis, int N, int NB, int E){
  __shared__ ull ebuf[BCAP];
  __shared__ ull obuf[BCAP];
  __shared__ int cnt[BNODES];
  __shared__ int cur[BNODES];
  __shared__ int w0tot;
  int b = blockIdx.x, t = threadIdx.x;
  int n0 = b << BSH;
  int n1 = n0 + BNODES; if (n1 > N) n1 = N;
  int gbeg = bbase[b];
  int gend = (b + 1 < NB) ? bbase[b + 1] : E;
  int cnt_all = gend - gbeg;
  cnt[t] = 0;
  __syncthreads();

  if (cnt_all <= BCAP){
    for (int i = t; i < cnt_all; i += BNODES){
      ull k = staging[gbeg + i];
      ebuf[i] = k;
      atomicAdd(&cnt[(int)(k >> LD_SH)], 1);
    }
    __syncthreads();
    int v = cnt[t];
    int lane = t & 63, wid = t >> 6;
    int x = v;
    for (int o = 1; o < 64; o <<= 1){ int y = __shfl_up(x, o, 64); if (lane >= o) x += y; }
    if (wid == 0 && lane == 63) w0tot = x;
    __syncthreads();
    int ls = x - v + (wid ? w0tot : 0);
    cur[t] = ls;
    int n = n0 + t;
    if (n < n1){
      float dd = (float)v + 1.0f;
      dis[n]  = __fdiv_rn(1.0f, __fsqrt_rn(dd));
      offs[n] = gbeg + ls;
    }
    __syncthreads();
    for (int i = t; i < cnt_all; i += BNODES){
      ull k = ebuf[i];
      int pos = atomicAdd(&cur[(int)(k >> LD_SH)], 1);
      obuf[pos] = k;
    }
    __syncthreads();
    for (int i = ls + 1; i < ls + v; i++){
      ull k = obuf[i]; int j = i - 1;
      while (j >= ls && obuf[j] > k){ obuf[j + 1] = obuf[j]; j--; }
      obuf[j + 1] = k;
    }
    __syncthreads();
    for (int i = t; i < cnt_all; i += BNODES)
      csr[gbeg + i] = (int)(obuf[i] & SRC_MASK);
  } else {
    // statistically unreachable fallback (correct, slow)
    int n = n0 + t;
    int deg = 0;
    if (n < n1){
      for (int i = gbeg; i < gend; i++) if ((int)(staging[i] >> LD_SH) == t) deg++;
      float dd = (float)deg + 1.0f;
      dis[n] = __fdiv_rn(1.0f, __fsqrt_rn(dd));
    }
    cnt[t] = (n < n1) ? deg : 0;
    __syncthreads();
    if (n < n1){
      int ls = gbeg; for (int q = 0; q < t; q++) ls += cnt[q];
      offs[n] = ls;
      ull prev = 0;
      for (int o = 0; o < deg; o++){
        ull best = ~0ull;
        for (int i = gbeg; i < gend; i++){
          ull k = staging[i];
          if ((int)(k >> LD_SH) == t && (o == 0 || k > prev) && k < best) best = k;
        }
        csr[ls + o] = (int)(best & SRC_MASK); prev = best;
      }
    }
  }
  if (b == 0 && t == 0) offs[N] = E;
}

// ---------------- per-node matmul h = x @ W ----------------
template<int K>
__global__ void node_matmul(const float* __restrict__ xin, const float* __restrict__ W,
                            float* __restrict__ H, int N){
  __shared__ float Ws[K * 32];
  for (int i = threadIdx.x; i < K * 32; i += blockDim.x) Ws[i] = W[i];
  __syncthreads();
  int tid = blockIdx.x * blockDim.x + threadIdx.x;
  int n = tid >> 5, c = tid & 31;
  if (n >= N) return;
  const float* xr = xin + (size_t)n * K;
  float acc = 0.f;
  #pragma unroll
  for (int k = 0; k < K; k++) acc = fmaf(xr[k], Ws[k * 32 + c], acc);
  H[(size_t)n * 32 + c] = acc;
}

// ---------------- GCN aggregation: 8 lanes/node x float4, exact edge order ----------
__device__ __forceinline__ float4 acc_edge(float4 a, float4 h, float w){
  a.x = __fadd_rn(a.x, __fmul_rn(h.x, w));
  a.y = __fadd_rn(a.y, __fmul_rn(h.y, w));
  a.z = __fadd_rn(a.z, __fmul_rn(h.z, w));
  a.w = __fadd_rn(a.w, __fmul_rn(h.w, w));
  return a;
}

__global__ __launch_bounds__(256) void agg_kernel(const float* __restrict__ H,
                           const int* __restrict__ offsets,
                           const int* __restrict__ csr, const float* __restrict__ dis,
                           const float* __restrict__ bias, float* __restrict__ A,
                           float* __restrict__ keyout, int N){
  int tid = blockIdx.x * 256 + threadIdx.x;
  int n = tid >> 3, qw = tid & 7;
  if (n >= N) return;
  const float4* __restrict__ H4 = (const float4*)H;
  float dn = dis[n];
  int s = offsets[n], e = offsets[n + 1];
  float4 acc = make_float4(0.f, 0.f, 0.f, 0.f);
  int i = s;
  for (; i + 4 <= e; i += 4){
    int s0 = csr[i], s1 = csr[i+1], s2 = csr[i+2], s3 = csr[i+3];
    float4 h0 = H4[(size_t)s0 * 8 + qw];
    float4 h1 = H4[(size_t)s1 * 8 + qw];
    float4 h2 = H4[(size_t)s2 * 8 + qw];
    float4 h3 = H4[(size_t)s3 * 8 + qw];
    float w0 = __fmul_rn(dis[s0], dn), w1 = __fmul_rn(dis[s1], dn);
    float w2 = __fmul_rn(dis[s2], dn), w3 = __fmul_rn(dis[s3], dn);
    acc = acc_edge(acc, h0, w0);
    acc = acc_edge(acc, h1, w1);
    acc = acc_edge(acc, h2, w2);
    acc = acc_edge(acc, h3, w3);
  }
  for (; i < e; i++){
    int sr = csr[i];
    float w = __fmul_rn(dis[sr], dn);
    acc = acc_edge(acc, H4[(size_t)sr * 8 + qw], w);
  }
  float4 hn = H4[(size_t)n * 8 + qw];
  float sw = __fmul_rn(dn, dn);
  float4 bb = ((const float4*)bias)[qw];
  float4 v;
  v.x = fmaxf(__fadd_rn(__fadd_rn(acc.x, __fmul_rn(hn.x, sw)), bb.x), 0.f);
  v.y = fmaxf(__fadd_rn(__fadd_rn(acc.y, __fmul_rn(hn.y, sw)), bb.y), 0.f);
  v.z = fmaxf(__fadd_rn(__fadd_rn(acc.z, __fmul_rn(hn.z, sw)), bb.z), 0.f);
  v.w = fmaxf(__fadd_rn(__fadd_rn(acc.w, __fmul_rn(hn.w, sw)), bb.w), 0.f);
  ((float4*)A)[(size_t)n * 8 + qw] = v;
  if (keyout != nullptr && qw == 7) keyout[n] = v.w;
}

// ---------------- graph boundaries (batch is sorted) ----------------
__global__ void gstarts_kernel(const int* __restrict__ batch, int* __restrict__ gstarts,
                               int N, int G){
  int g = blockIdx.x * blockDim.x + threadIdx.x;
  if (g > G) return;
  int lo = 0, hi = N;
  while (lo < hi){ int mid = (lo + hi) >> 1; if (batch[mid] < g) lo = mid + 1; else hi = mid; }
  gstarts[g] = lo;
}

// ------- fused head: swizzled float4-LDS convs, tiny per-thread state ---------
__global__ __launch_bounds__(128) void head_kernel(
    const float* __restrict__ A, const float* __restrict__ keys,
    const int* __restrict__ gstarts,
    const float* __restrict__ cw1, const float* __restrict__ cb1,
    const float* __restrict__ cw2, const float* __restrict__ cb2,
    const float* __restrict__ lw1, const float* __restrict__ lb1,
    const float* __restrict__ lw2, const float* __restrict__ lb2,
    float* __restrict__ out){
  int g = blockIdx.x;
  int t = threadIdx.x;
  __shared__ float w1s[16 * W1STR];       // [o][k*32 + ch]
  __shared__ float w2s[32 * W2STR];       // [o][k*16 + ch]
  __shared__ float sin_[SINROWS * 32];    // [row][ch], float4-swizzled by (i4^(row&7))
  __shared__ float c1[C1ROWS * 16];       // [row][ch], float4-swizzled by (i2^(row&3))
  __shared__ float c2[22 * C2ROW];        // [pos][ch], plain
  __shared__ float d1[128];
  __shared__ float kbuf[KCAP];
  __shared__ int   sel[SORTK];

  // stage transposed conv weights
  for (int idx = t; idx < 2560; idx += 128){
    int o = idx / 160, r = idx - o * 160, ch = r / 5, k = r - ch * 5;
    w1s[o * W1STR + k * 32 + ch] = cw1[idx];
  }
  for (int idx = t; idx < 2560; idx += 128){
    int o = idx / 80, r = idx - o * 80, ch = r / 5, k = r - ch * 5;
    w2s[o * W2STR + k * 16 + ch] = cw2[idx];
  }
  for (int i = t; i < SINROWS * 32; i += 128) sin_[i] = 0.f;
  for (int i = t; i < C1ROWS * 16; i += 128) c1[i] = 0.f;

  int s = gstarts[g], e = gstarts[g + 1];
  int c = e - s;
  bool fast = (c <= KCAP);
  if (fast) for (int i = t; i < c; i += 128) kbuf[i] = keys[s + i];
  __syncthreads();

  // stable top-30 rank: key desc, index asc (bit-identical selection)
  for (int i = t; i < c; i += 128){
    float ki = fast ? kbuf[i] : keys[s + i];
    int rank = 0; bool ok = true;
    for (int j = 0; j < c; j++){
      float kj = fast ? kbuf[j] : keys[s + j];
      if (kj > ki || (kj == ki && j < i)){
        if (++rank >= SORTK){ ok = false; break; }
      }
    }
    if (ok) sel[rank] = i;
  }
  __syncthreads();

  // gather selected rows: sin_[pos][ch] swizzled (coalesced A reads)
  int kk = c < SORTK ? c : SORTK;
  for (int q = t; q < kk * 32; q += 128){
    int pos = q >> 5, ch = q & 31;
    int i4 = ch >> 2, li = ch & 3;
    sin_[(pos << 5) + (((i4 ^ (pos & 7))) << 2) + li] =
        A[(size_t)(s + sel[pos]) * 32 + ch];
  }
  __syncthreads();

  // conv1: (32ch,30) -> (16ch,26). thread = (o = t&15, base = t>>4); passes tt = base+8p
  {
    int o = t & 15, base = t >> 4;
    float cb = cb1[o];
    float acc[4] = {cb, cb, cb, cb};
    for (int i4 = 0; i4 < 8; i4++){
      float4 wk[5];
      #pragma unroll
      for (int k = 0; k < 5; k++)
        wk[k] = *(const float4*)&w1s[o * W1STR + k * 32 + (i4 << 2)];
      #pragma unroll
      for (int p = 0; p < 4; p++){
        int tt = base + (p << 3);
        #pragma unroll
        for (int k = 0; k < 5; k++){
          int row = tt + k;   // <= 35 < SINROWS, pad rows are zero
          float4 sv = *(const float4*)&sin_[(row << 5) + ((i4 ^ (row & 7)) << 2)];
          float4 wv = wk[k];
          acc[p] = fmaf(sv.x, wv.x, acc[p]);
          acc[p] = fmaf(sv.y, wv.y, acc[p]);
          acc[p] = fmaf(sv.z, wv.z, acc[p]);
          acc[p] = fmaf(sv.w, wv.w, acc[p]);
        }
      }
    }
    #pragma unroll
    for (int p = 0; p < 4; p++){
      int tt = base + (p << 3);
      if (tt < 26)
        c1[(tt << 4) + (((o >> 2) ^ (tt & 3)) << 2) + (o & 3)] = fmaxf(acc[p], 0.f);
    }
  }
  __syncthreads();

  // conv2: (16ch,26) -> (32ch,22). thread = (o = t&31, base = t>>5); passes tt = base+4p
  {
    int o = t & 31, base = t >> 5;
    float cb = cb2[o];
    float acc[6] = {cb, cb, cb, cb, cb, cb};
    for (int i4 = 0; i4 < 4; i4++){
      float4 wk[5];
      #pragma unroll
      for (int k = 0; k < 5; k++)
        wk[k] = *(const float4*)&w2s[o * W2STR + k * 16 + (i4 << 2)];
      #pragma unroll
      for (int p = 0; p < 6; p++){
        int tt = base + (p << 2);
        #pragma unroll
        for (int k = 0; k < 5; k++){
          int row = tt + k;   // <= 27 < C1ROWS, pad rows are zero
          float4 sv = *(const float4*)&c1[(row << 4) + ((i4 ^ (row & 3)) << 2)];
          float4 wv = wk[k];
          acc[p] = fmaf(sv.x, wv.x, acc[p]);
          acc[p] = fmaf(sv.y, wv.y, acc[p]);
          acc[p] = fmaf(sv.z, wv.z, acc[p]);
          acc[p] = fmaf(sv.w, wv.w, acc[p]);
        }
      }
    }
    #pragma unroll
    for (int p = 0; p < 6; p++){
      int tt = base + (p << 2);
      if (tt < 22) c2[tt * C2ROW + o] = fmaxf(acc[p], 0.f);
    }
  }
  __syncthreads();

  // dense1: 704 -> 128; flatten j = ch*22 + pos (reference reshape order)
  {
    float acc = lb1[t];
    int j = 0;
    for (int ch = 0; ch < 32; ch++){
      for (int pos = 0; pos < 22; pos++){
        acc = fmaf(c2[pos * C2ROW + ch], lw1[(size_t)j * 128 + t], acc);
        j++;
      }
    }
    d1[t] = fmaxf(acc, 0.f);
  }
  __syncthreads();

  // dense2: 128 -> 1
  if (t == 0){
    float acc = lb2[0];
    for (int o = 0; o < 128; o++) acc = fmaf(d1[o], lw2[o], acc);
    out[g] = acc;
  }
}

// ---------------- launch ----------------
extern "C" void kernel_launch(void* const* d_in, const int* in_sizes, int n_in,
                              void* d_out, int out_size, void* d_ws, size_t ws_size,
                              hipStream_t stream){
  const float* x     = (const float*)d_in[0];
  const int*   ei    = (const int*)  d_in[1];
  const int*   batch = (const int*)  d_in[2];
  const float* W1  = (const float*)d_in[4];
  const float* b1  = (const float*)d_in[5];
  const float* W2  = (const float*)d_in[6];
  const float* b2  = (const float*)d_in[7];
  const float* W3  = (const float*)d_in[8];
  const float* b3  = (const float*)d_in[9];
  const float* cw1 = (const float*)d_in[10];
  const float* cb1 = (const float*)d_in[11];
  const float* cw2 = (const float*)d_in[12];
  const float* cb2 = (const float*)d_in[13];
  const float* lw1 = (const float*)d_in[14];
  const float* lb1 = (const float*)d_in[15];
  const float* lw2 = (const float*)d_in[16];
  const float* lb2 = (const float*)d_in[17];

  int N = in_sizes[0] / 9;
  int E = in_sizes[1] / 2;
  int G = out_size;
  const int* srcs = ei;
  const int* dsts = ei + E;
  int NB = ceil_div_i(N, BNODES);
  int segsz = ceil_div_i(E, NSEG);

  char* base = (char*)d_ws;
  size_t off = 0;
  auto alloc = [&](size_t bytes) -> void* {
    off = (off + 255) & ~(size_t)255;
    void* r = base + off; off += bytes; return r;
  };
  float* dis    = (float*)alloc((size_t)N * 4);
  float* H      = (float*)alloc((size_t)N * 32 * 4);   // aliased as staging
  float* A      = (float*)alloc((size_t)N * 32 * 4);
  float* keyarr = (float*)alloc((size_t)N * 4);
  int*   offs   = (int*)alloc((size_t)(N + 1) * 4);
  int*   csr    = (int*)alloc((size_t)E * 4);
  int*   gst    = (int*)alloc((size_t)(G + 1) * 4);
  int*   hist   = (int*)alloc((size_t)NSEG * NB * 4);
  int*   segoff = (int*)alloc((size_t)NSEG * NB * 4);
  int*   btot   = (int*)alloc((size_t)NB * 4);
  int*   bbase  = (int*)alloc((size_t)(NB + 1) * 4);
  ull*   staging = (ull*)H;
  (void)ws_size; (void)n_in;

  hist_kernel<<<NSEG, 1024, 0, stream>>>(dsts, hist, E, NB, segsz);
  segscanA<<<ceil_div_i(NB, 256), 256, 0, stream>>>(hist, segoff, btot, NB, NSEG);
  segscanB<<<1, 1024, 0, stream>>>(btot, bbase, NB);
  scatter_kernel<<<NSEG, 1024, 0, stream>>>(dsts, srcs, segoff, bbase, staging, E, NB, segsz);
  bucket_sort_kernel<<<NB, BNODES, 0, stream>>>(bbase, staging, csr, offs, dis, N, NB, E);

  int ntm = ceil_div_i((long long)N * 32, 256);
  int nta = ceil_div_i((long long)N * 8, 256);
  node_matmul<9><<<ntm, 256, 0, stream>>>(x, W1, H, N);
  agg_kernel<<<nta, 256, 0, stream>>>(H, offs, csr, dis, b1, A, nullptr, N);
  node_matmul<32><<<ntm, 256, 0, stream>>>(A, W2, H, N);
  agg_kernel<<<nta, 256, 0, stream>>>(H, offs, csr, dis, b2, A, nullptr, N);
  node_matmul<32><<<ntm, 256, 0, stream>>>(A, W3, H, N);
  agg_kernel<<<nta, 256, 0, stream>>>(H, offs, csr, dis, b3, A, keyarr, N);

  gstarts_kernel<<<ceil_div_i(G + 1, 256), 256, 0, stream>>>(batch, gst, N, G);
  head_kernel<<<G, 128, 0, stream>>>(A, keyarr, gst, cw1, cb1, cw2, cb2,
                                     lw1, lb1, lw2, lb2, (float*)d_out);
}

// Round 9
// 630.124 us; speedup vs baseline: 1.2572x; 1.2572x over previous
//
#include <hip/hip_runtime.h>

typedef unsigned long long ull;

#define HIDDEN 32
#define SORTK 30
#define KCAP 256              // max nodes/graph fast path (mean 122, sd 11; 12 sigma)
#define GPB 2                 // graphs per head block (shared weight stage)
#define BSH 7                 // 128 nodes per bucket
#define BNODES (1 << BSH)
#define BCAP 1536
#define HMAX 2048
#define NSEG 256
#define SRC_BITS 18
#define SRC_MASK ((1u << SRC_BITS) - 1)
#define EID_SH  SRC_BITS
#define LD_SH   (SRC_BITS + 22)

static inline int ceil_div_i(long long a, int b){ return (int)((a + b - 1) / b); }

// ---------------- phase 1: per-segment LDS histogram ----------------
__global__ __launch_bounds__(1024) void hist_kernel(const int* __restrict__ dsts,
                                                    int* __restrict__ hist,
                                                    int E, int NB, int segsz){
  __shared__ int h[HMAX];
  for (int i = threadIdx.x; i < NB; i += 1024) h[i] = 0;
  __syncthreads();
  int seg = blockIdx.x;
  int e0 = seg * segsz;
  int e1 = e0 + segsz; if (e1 > E) e1 = E;
  for (int e = e0 + threadIdx.x; e < e1; e += 1024)
    atomicAdd(&h[dsts[e] >> BSH], 1);
  __syncthreads();
  for (int i = threadIdx.x; i < NB; i += 1024) hist[seg * NB + i] = h[i];
}

// ---------------- phase 2a: per-bucket running prefix over segments ----------------
__global__ __launch_bounds__(256) void segscanA(const int* __restrict__ hist,
                                                int* __restrict__ segoff,
                                                int* __restrict__ btot,
                                                int NB, int S){
  int b = blockIdx.x * 256 + threadIdx.x;
  if (b >= NB) return;
  int run = 0;
  for (int s = 0; s < S; s++){
    int v = hist[s * NB + b];
    segoff[s * NB + b] = run;
    run += v;
  }
  btot[b] = run;
}

// ---------------- phase 2b: exclusive scan of bucket totals (1 block) ----------------
__global__ __launch_bounds__(1024) void segscanB(const int* __restrict__ btot,
                                                 int* __restrict__ bbase, int NB){
  int t = threadIdx.x;
  int b0 = t * 2, b1 = t * 2 + 1;
  int v0 = (b0 < NB) ? btot[b0] : 0;
  int v1 = (b1 < NB) ? btot[b1] : 0;
  int pair = v0 + v1;
  int lane = t & 63, wid = t >> 6;
  int x = pair;
  for (int o = 1; o < 64; o <<= 1){ int y = __shfl_up(x, o, 64); if (lane >= o) x += y; }
  __shared__ int wsum[16]; __shared__ int woff[16];
  if (lane == 63) wsum[wid] = x;
  __syncthreads();
  if (t == 0){ int run = 0; for (int w = 0; w < 16; w++){ woff[w] = run; run += wsum[w]; } }
  __syncthreads();
  int excl = x - pair + woff[wid];
  if (b0 < NB) bbase[b0] = excl;
  if (b1 < NB) bbase[b1] = excl + v0;
}

// ---------------- phase 3: scatter 64-bit (ld,eid,src), block-private regions ------
__global__ __launch_bounds__(1024) void scatter_kernel(const int* __restrict__ dsts,
                                                       const int* __restrict__ srcs,
                                                       const int* __restrict__ segoff,
                                                       const int* __restrict__ bbase,
                                                       ull* __restrict__ staging,
                                                       int E, int NB, int segsz){
  __shared__ int cur[HMAX];
  int seg = blockIdx.x;
  for (int i = threadIdx.x; i < NB; i += 1024) cur[i] = segoff[seg * NB + i] + bbase[i];
  __syncthreads();
  int e0 = seg * segsz;
  int e1 = e0 + segsz; if (e1 > E) e1 = E;
  for (int e = e0 + threadIdx.x; e < e1; e += 1024){
    int d = dsts[e];
    int slot = atomicAdd(&cur[d >> BSH], 1);
    staging[slot] = ((ull)(d & (BNODES - 1)) << LD_SH) | ((ull)e << EID_SH)
                  | (ull)(unsigned)srcs[e];
  }
}

// ---------------- phase 4: per-bucket LDS sort + dis + offs + CSR ----------------
__global__ __launch_bounds__(BNODES) void bucket_sort_kernel(
    const int* __restrict__ bbase, const ull* __restrict__ staging,
    int* __restrict__ csr, int* __restrict__ offs,
    float* __restrict__ dis, int N, int NB, int E){
  __shared__ ull ebuf[BCAP];
  __shared__ ull obuf[BCAP];
  __shared__ int cnt[BNODES];
  __shared__ int cur[BNODES];
  __shared__ int w0tot;
  int b = blockIdx.x, t = threadIdx.x;
  int n0 = b << BSH;
  int n1 = n0 + BNODES; if (n1 > N) n1 = N;
  int gbeg = bbase[b];
  int gend = (b + 1 < NB) ? bbase[b + 1] : E;
  int cnt_all = gend - gbeg;
  cnt[t] = 0;
  __syncthreads();

  if (cnt_all <= BCAP){
    for (int i = t; i < cnt_all; i += BNODES){
      ull k = staging[gbeg + i];
      ebuf[i] = k;
      atomicAdd(&cnt[(int)(k >> LD_SH)], 1);
    }
    __syncthreads();
    int v = cnt[t];
    int lane = t & 63, wid = t >> 6;
    int x = v;
    for (int o = 1; o < 64; o <<= 1){ int y = __shfl_up(x, o, 64); if (lane >= o) x += y; }
    if (wid == 0 && lane == 63) w0tot = x;
    __syncthreads();
    int ls = x - v + (wid ? w0tot : 0);
    cur[t] = ls;
    int n = n0 + t;
    if (n < n1){
      float dd = (float)v + 1.0f;
      dis[n]  = __fdiv_rn(1.0f, __fsqrt_rn(dd));
      offs[n] = gbeg + ls;
    }
    __syncthreads();
    for (int i = t; i < cnt_all; i += BNODES){
      ull k = ebuf[i];
      int pos = atomicAdd(&cur[(int)(k >> LD_SH)], 1);
      obuf[pos] = k;
    }
    __syncthreads();
    for (int i = ls + 1; i < ls + v; i++){
      ull k = obuf[i]; int j = i - 1;
      while (j >= ls && obuf[j] > k){ obuf[j + 1] = obuf[j]; j--; }
      obuf[j + 1] = k;
    }
    __syncthreads();
    for (int i = t; i < cnt_all; i += BNODES)
      csr[gbeg + i] = (int)(obuf[i] & SRC_MASK);
  } else {
    // statistically unreachable fallback (correct, slow)
    int n = n0 + t;
    int deg = 0;
    if (n < n1){
      for (int i = gbeg; i < gend; i++) if ((int)(staging[i] >> LD_SH) == t) deg++;
      float dd = (float)deg + 1.0f;
      dis[n] = __fdiv_rn(1.0f, __fsqrt_rn(dd));
    }
    cnt[t] = (n < n1) ? deg : 0;
    __syncthreads();
    if (n < n1){
      int ls = gbeg; for (int q = 0; q < t; q++) ls += cnt[q];
      offs[n] = ls;
      ull prev = 0;
      for (int o = 0; o < deg; o++){
        ull best = ~0ull;
        for (int i = gbeg; i < gend; i++){
          ull k = staging[i];
          if ((int)(k >> LD_SH) == t && (o == 0 || k > prev) && k < best) best = k;
        }
        csr[ls + o] = (int)(best & SRC_MASK); prev = best;
      }
    }
  }
  if (b == 0 && t == 0) offs[N] = E;
}

// ---------------- per-node matmul h = x @ W ----------------
template<int K>
__global__ void node_matmul(const float* __restrict__ xin, const float* __restrict__ W,
                            float* __restrict__ H, int N){
  __shared__ float Ws[K * 32];
  for (int i = threadIdx.x; i < K * 32; i += blockDim.x) Ws[i] = W[i];
  __syncthreads();
  int tid = blockIdx.x * blockDim.x + threadIdx.x;
  int n = tid >> 5, c = tid & 31;
  if (n >= N) return;
  const float* xr = xin + (size_t)n * K;
  float acc = 0.f;
  #pragma unroll
  for (int k = 0; k < K; k++) acc = fmaf(xr[k], Ws[k * 32 + c], acc);
  H[(size_t)n * 32 + c] = acc;
}

// ---------------- GCN aggregation: 8 lanes/node x float4, exact edge order ----------
__device__ __forceinline__ float4 acc_edge(float4 a, float4 h, float w){
  a.x = __fadd_rn(a.x, __fmul_rn(h.x, w));
  a.y = __fadd_rn(a.y, __fmul_rn(h.y, w));
  a.z = __fadd_rn(a.z, __fmul_rn(h.z, w));
  a.w = __fadd_rn(a.w, __fmul_rn(h.w, w));
  return a;
}

__global__ __launch_bounds__(256) void agg_kernel(const float* __restrict__ H,
                           const int* __restrict__ offsets,
                           const int* __restrict__ csr, const float* __restrict__ dis,
                           const float* __restrict__ bias, float* __restrict__ A,
                           float* __restrict__ keyout, int N){
  int tid = blockIdx.x * 256 + threadIdx.x;
  int n = tid >> 3, qw = tid & 7;
  if (n >= N) return;
  const float4* __restrict__ H4 = (const float4*)H;
  float dn = dis[n];
  int s = offsets[n], e = offsets[n + 1];
  float4 acc = make_float4(0.f, 0.f, 0.f, 0.f);
  int i = s;
  for (; i + 4 <= e; i += 4){
    int s0 = csr[i], s1 = csr[i+1], s2 = csr[i+2], s3 = csr[i+3];
    float4 h0 = H4[(size_t)s0 * 8 + qw];
    float4 h1 = H4[(size_t)s1 * 8 + qw];
    float4 h2 = H4[(size_t)s2 * 8 + qw];
    float4 h3 = H4[(size_t)s3 * 8 + qw];
    float w0 = __fmul_rn(dis[s0], dn), w1 = __fmul_rn(dis[s1], dn);
    float w2 = __fmul_rn(dis[s2], dn), w3 = __fmul_rn(dis[s3], dn);
    acc = acc_edge(acc, h0, w0);
    acc = acc_edge(acc, h1, w1);
    acc = acc_edge(acc, h2, w2);
    acc = acc_edge(acc, h3, w3);
  }
  for (; i < e; i++){
    int sr = csr[i];
    float w = __fmul_rn(dis[sr], dn);
    acc = acc_edge(acc, H4[(size_t)sr * 8 + qw], w);
  }
  float4 hn = H4[(size_t)n * 8 + qw];
  float sw = __fmul_rn(dn, dn);
  float4 bb = ((const float4*)bias)[qw];
  float4 v;
  v.x = fmaxf(__fadd_rn(__fadd_rn(acc.x, __fmul_rn(hn.x, sw)), bb.x), 0.f);
  v.y = fmaxf(__fadd_rn(__fadd_rn(acc.y, __fmul_rn(hn.y, sw)), bb.y), 0.f);
  v.z = fmaxf(__fadd_rn(__fadd_rn(acc.z, __fmul_rn(hn.z, sw)), bb.z), 0.f);
  v.w = fmaxf(__fadd_rn(__fadd_rn(acc.w, __fmul_rn(hn.w, sw)), bb.w), 0.f);
  ((float4*)A)[(size_t)n * 8 + qw] = v;
  if (keyout != nullptr && qw == 7) keyout[n] = v.w;
}

// ---------------- graph boundaries (batch is sorted) ----------------
__global__ void gstarts_kernel(const int* __restrict__ batch, int* __restrict__ gstarts,
                               int N, int G){
  int g = blockIdx.x * blockDim.x + threadIdx.x;
  if (g > G) return;
  int lo = 0, hi = N;
  while (lo < hi){ int mid = (lo + hi) >> 1; if (batch[mid] < g) lo = mid + 1; else hi = mid; }
  gstarts[g] = lo;
}

// ------- fused head: 2 graphs per block, shared weight stage, r6 scalar convs ---------
__global__ __launch_bounds__(256) void head_kernel(
    const float* __restrict__ A, const float* __restrict__ keys,
    const int* __restrict__ gstarts,
    const float* __restrict__ cw1, const float* __restrict__ cb1,
    const float* __restrict__ cw2, const float* __restrict__ cb2,
    const float* __restrict__ lw1, const float* __restrict__ lb1,
    const float* __restrict__ lw2, const float* __restrict__ lb2,
    float* __restrict__ out, int G){
  int t = threadIdx.x;
  int sub = t >> 7, lt = t & 127;
  int g = blockIdx.x * GPB + sub;

  __shared__ float w1s[16 * 32 * 5];      // shared by both graphs
  __shared__ float w2s[32 * 16 * 5];
  __shared__ float sin_[GPB][32 * 30];
  __shared__ float c1[GPB][16 * 26];
  __shared__ float c2[GPB][32 * 22];
  __shared__ float d1[GPB][128];
  __shared__ float kbuf[GPB][KCAP];
  __shared__ int   sel[GPB][SORTK];

  for (int i = t; i < 2560; i += 256) w1s[i] = cw1[i];
  for (int i = t; i < 2560; i += 256) w2s[i] = cw2[i];
  for (int i = lt; i < 960; i += 128) sin_[sub][i] = 0.f;

  bool valid = (g < G);
  int s = 0, c = 0;
  if (valid){ s = gstarts[g]; c = gstarts[g + 1] - s; }
  bool fast = (c <= KCAP);
  if (valid && fast)
    for (int i = lt; i < c; i += 128) kbuf[sub][i] = keys[s + i];  // coalesced
  __syncthreads();

  // stable top-30 rank: key desc, index asc (bit-identical selection)
  if (valid){
    for (int i = lt; i < c; i += 128){
      float ki = fast ? kbuf[sub][i] : keys[s + i];
      int rank = 0; bool ok = true;
      for (int j = 0; j < c; j++){
        float kj = fast ? kbuf[sub][j] : keys[s + j];
        if (kj > ki || (kj == ki && j < i)){
          if (++rank >= SORTK){ ok = false; break; }
        }
      }
      if (ok) sel[sub][rank] = i;
    }
  }
  __syncthreads();

  // gather selected rows into conv layout sin_[ch*30+pos] (coalesced A reads)
  if (valid){
    int kk = c < SORTK ? c : SORTK;
    for (int q = lt; q < kk * 32; q += 128){
      int pos = q >> 5, ch = q & 31;
      sin_[sub][ch * 30 + pos] = A[(size_t)(s + sel[sub][pos]) * 32 + ch];
    }
  }
  __syncthreads();

  // conv1: (32,30) -> (16,26)
  if (valid){
    for (int q = lt; q < 16 * 26; q += 128){
      int o = q / 26, tt = q % 26;
      float acc = cb1[o];
      const float* wo = &w1s[o * 160];
      for (int i = 0; i < 32; i++){
        const float* si = &sin_[sub][i * 30 + tt];
        #pragma unroll
        for (int k = 0; k < 5; k++) acc = fmaf(si[k], wo[i * 5 + k], acc);
      }
      c1[sub][q] = fmaxf(acc, 0.f);
    }
  }
  __syncthreads();

  // conv2: (16,26) -> (32,22)
  if (valid){
    for (int q = lt; q < 32 * 22; q += 128){
      int o = q / 22, tt = q % 22;
      float acc = cb2[o];
      const float* wo = &w2s[o * 80];
      for (int i = 0; i < 16; i++){
        const float* si = &c1[sub][i * 26 + tt];
        #pragma unroll
        for (int k = 0; k < 5; k++) acc = fmaf(si[k], wo[i * 5 + k], acc);
      }
      c2[sub][q] = fmaxf(acc, 0.f);
    }
  }
  __syncthreads();

  // dense1: 704 -> 128 (both sub-groups stream lw1 in lockstep -> L1 reuse)
  if (valid){
    float acc = lb1[lt];
    for (int j = 0; j < 704; j++) acc = fmaf(c2[sub][j], lw1[(size_t)j * 128 + lt], acc);
    d1[sub][lt] = fmaxf(acc, 0.f);
  }
  __syncthreads();

  // dense2: 128 -> 1
  if (valid && lt == 0){
    float acc = lb2[0];
    for (int o = 0; o < 128; o++) acc = fmaf(d1[sub][o], lw2[o], acc);
    out[g] = acc;
  }
}

// ---------------- launch ----------------
extern "C" void kernel_launch(void* const* d_in, const int* in_sizes, int n_in,
                              void* d_out, int out_size, void* d_ws, size_t ws_size,
                              hipStream_t stream){
  const float* x     = (const float*)d_in[0];
  const int*   ei    = (const int*)  d_in[1];
  const int*   batch = (const int*)  d_in[2];
  const float* W1  = (const float*)d_in[4];
  const float* b1  = (const float*)d_in[5];
  const float* W2  = (const float*)d_in[6];
  const float* b2  = (const float*)d_in[7];
  const float* W3  = (const float*)d_in[8];
  const float* b3  = (const float*)d_in[9];
  const float* cw1 = (const float*)d_in[10];
  const float* cb1 = (const float*)d_in[11];
  const float* cw2 = (const float*)d_in[12];
  const float* cb2 = (const float*)d_in[13];
  const float* lw1 = (const float*)d_in[14];
  const float* lb1 = (const float*)d_in[15];
  const float* lw2 = (const float*)d_in[16];
  const float* lb2 = (const float*)d_in[17];

  int N = in_sizes[0] / 9;
  int E = in_sizes[1] / 2;
  int G = out_size;
  const int* srcs = ei;
  const int* dsts = ei + E;
  int NB = ceil_div_i(N, BNODES);
  int segsz = ceil_div_i(E, NSEG);

  char* base = (char*)d_ws;
  size_t off = 0;
  auto alloc = [&](size_t bytes) -> void* {
    off = (off + 255) & ~(size_t)255;
    void* r = base + off; off += bytes; return r;
  };
  float* dis    = (float*)alloc((size_t)N * 4);
  float* H      = (float*)alloc((size_t)N * 32 * 4);   // aliased as staging
  float* A      = (float*)alloc((size_t)N * 32 * 4);
  float* keyarr = (float*)alloc((size_t)N * 4);
  int*   offs   = (int*)alloc((size_t)(N + 1) * 4);
  int*   csr    = (int*)alloc((size_t)E * 4);
  int*   gst    = (int*)alloc((size_t)(G + 1) * 4);
  int*   hist   = (int*)alloc((size_t)NSEG * NB * 4);
  int*   segoff = (int*)alloc((size_t)NSEG * NB * 4);
  int*   btot   = (int*)alloc((size_t)NB * 4);
  int*   bbase  = (int*)alloc((size_t)(NB + 1) * 4);
  ull*   staging = (ull*)H;
  (void)ws_size; (void)n_in;

  hist_kernel<<<NSEG, 1024, 0, stream>>>(dsts, hist, E, NB, segsz);
  segscanA<<<ceil_div_i(NB, 256), 256, 0, stream>>>(hist, segoff, btot, NB, NSEG);
  segscanB<<<1, 1024, 0, stream>>>(btot, bbase, NB);
  scatter_kernel<<<NSEG, 1024, 0, stream>>>(dsts, srcs, segoff, bbase, staging, E, NB, segsz);
  bucket_sort_kernel<<<NB, BNODES, 0, stream>>>(bbase, staging, csr, offs, dis, N, NB, E);

  int ntm = ceil_div_i((long long)N * 32, 256);
  int nta = ceil_div_i((long long)N * 8, 256);
  node_matmul<9><<<ntm, 256, 0, stream>>>(x, W1, H, N);
  agg_kernel<<<nta, 256, 0, stream>>>(H, offs, csr, dis, b1, A, nullptr, N);
  node_matmul<32><<<ntm, 256, 0, stream>>>(A, W2, H, N);
  agg_kernel<<<nta, 256, 0, stream>>>(H, offs, csr, dis, b2, A, nullptr, N);
  node_matmul<32><<<ntm, 256, 0, stream>>>(A, W3, H, N);
  agg_kernel<<<nta, 256, 0, stream>>>(H, offs, csr, dis, b3, A, keyarr, N);

  gstarts_kernel<<<ceil_div_i(G + 1, 256), 256, 0, stream>>>(batch, gst, N, G);
  head_kernel<<<ceil_div_i(G, GPB), 256, 0, stream>>>(A, keyarr, gst, cw1, cb1, cw2, cb2,
                                                      lw1, lb1, lw2, lb2, (float*)d_out, G);
}